// Round 13
// baseline (316.452 us; speedup 1.0000x reference)
//
#include <hip/hip_runtime.h>
#include <hip/hip_bf16.h>
#include <math.h>

typedef __attribute__((ext_vector_type(4))) float f32x4;
typedef __attribute__((ext_vector_type(16))) float f32x16;
typedef __attribute__((ext_vector_type(4))) int i32x4;
typedef __attribute__((ext_vector_type(8))) int v8i;

#define N 8192
#define D 256
#define INV_T 10.0f
#define EPSN 1e-8f
#define NBLK 1056

__device__ __forceinline__ void async16(void* lds, const void* g) {
  __builtin_amdgcn_global_load_lds(
      (const __attribute__((address_space(1))) void*)g,
      (__attribute__((address_space(3))) void*)lds,
      16, 0, 0);
}

// 16-lane-group sum via DPP row_shr (VALU pipe). Result in lane 15 of group.
__device__ __forceinline__ float rowsum16(float v) {
  v += __uint_as_float(__builtin_amdgcn_update_dpp(
      0u, __float_as_uint(v), 0x118, 0xf, 0xf, true));
  v += __uint_as_float(__builtin_amdgcn_update_dpp(
      0u, __float_as_uint(v), 0x114, 0xf, 0xf, true));
  v += __uint_as_float(__builtin_amdgcn_update_dpp(
      0u, __float_as_uint(v), 0x112, 0xf, 0xf, true));
  v += __uint_as_float(__builtin_amdgcn_update_dpp(
      0u, __float_as_uint(v), 0x111, 0xf, 0xf, true));
  return v;
}

// 32-lane-group sum: rowsum16 + ROW_BCAST15 (0x142). Result in lanes 31, 63.
__device__ __forceinline__ float rowsum32(float v) {
  v = rowsum16(v);
  v += __uint_as_float(__builtin_amdgcn_update_dpp(
      0u, __float_as_uint(v), 0x142, 0xf, 0xf, true));
  return v;
}

// One wave per row: fp32 norm, fp8-e4m3 normalized row. Zeroes rowsum + cnt.
__global__ __launch_bounds__(256) void normalize_k(const float* __restrict__ feats,
                                                   unsigned char* __restrict__ fn,
                                                   float* __restrict__ rowsum,
                                                   unsigned int* __restrict__ cnt) {
  int row = blockIdx.x * 4 + (threadIdx.x >> 6);
  int lane = threadIdx.x & 63;
  if (threadIdx.x < 4) rowsum[blockIdx.x * 4 + threadIdx.x] = 0.0f;
  if (blockIdx.x == 0 && threadIdx.x == 0) *cnt = 0u;
  float4 v = ((const float4*)(feats + (size_t)row * D))[lane];
  float ss = v.x * v.x + v.y * v.y + v.z * v.z + v.w * v.w;
#pragma unroll
  for (int off = 32; off; off >>= 1) ss += __shfl_xor(ss, off, 64);
  float inv = 1.0f / fmaxf(sqrtf(ss), EPSN);
  int w = __builtin_amdgcn_cvt_pk_fp8_f32(v.x * inv, v.y * inv, 0, false);
  w = __builtin_amdgcn_cvt_pk_fp8_f32(v.z * inv, v.w * inv, w, true);
  ((int*)(fn + (size_t)row * D))[lane] = w;
}

// Fused symmetric GEMM (C = fn*fn^T/T, fp8 via MX-scaled 32x32x64 MFMA with
// unit scales -> 2x the non-scaled fp8 rate) + exp(C-10) row/col sums + pos
// harvest + fused final reduction (last-block-done).
// PAIRED tiles: block = 128x256 strip (two 128^2 triangular tiles, shared A
// panel). 8 waves (2x4), each owns 64x64 = 2x2 32x32 frags. BK=64,
// counted-vmcnt double-buffer, chunk-swizzled LDS, DPP reductions.
// launch_bounds (512,4): VGPR cap 128; acc(64)+a/b(32) must not spill (R11).
__global__ __launch_bounds__(512, 4) void gemm_lse(const unsigned char* __restrict__ fn,
                                                   float* __restrict__ rowsum,
                                                   float* __restrict__ pos,
                                                   unsigned int* __restrict__ cnt,
                                                   float* __restrict__ out) {
  __shared__ __align__(16) unsigned char As[2][8192];    // 128 rows x 64B
  __shared__ __align__(16) unsigned char Bs[2][16384];   // 256 rows x 64B
  __shared__ float lrow[128];
  __shared__ float lcol[256];
  __shared__ int lastFlag;
  int tid = threadIdx.x;
  int wave = tid >> 6, lane = tid & 63;
  int wm = wave >> 2, wn = wave & 3;
  int l31 = lane & 31, h = lane >> 5;

  // XCD-chunked order over 1056 = 8*132 blocks (bijective).
  int b = blockIdx.x;
  int t = (b & 7) * 132 + (b >> 3);
  int hh = (int)((65.0f - sqrtf((float)(4225 - 4 * t))) * 0.5f);
  hh = hh < 0 ? 0 : (hh > 31 ? 31 : hh);
  while (t < hh * (65 - hh)) --hh;
  while (t >= (hh + 1) * (64 - hh)) ++hh;
  int r = t - hh * (65 - hh);
  int bm = 2 * hh + (r & 1);  // A-panel tile, 0..63
  int p = hh + (r >> 1);      // B pair index: bn in {2p, 2p+1}

  const unsigned char* ga = fn + (size_t)(bm * 128) * D;
  const unsigned char* gb = fn + (size_t)(p * 256) * D;

  // Staging: chunk swizzle c' = c ^ ((r>>1)&3) within 4-chunk (64B) rows.
  int da = tid, ra = da >> 2, caa = ((da & 3) ^ ((ra >> 1) & 3)) * 16;
  int d0 = tid, r0 = d0 >> 2, c0 = ((d0 & 3) ^ ((r0 >> 1) & 3)) * 16;
  int d1 = tid + 512, r1 = d1 >> 2, c1 = ((d1 & 3) ^ ((r1 >> 1) & 3)) * 16;
  auto stage = [&](int buf, int kt) {
    async16(&As[buf][da * 16], ga + (size_t)ra * D + kt * 64 + caa);
    async16(&Bs[buf][d0 * 16], gb + (size_t)r0 * D + kt * 64 + c0);
    async16(&Bs[buf][d1 * 16], gb + (size_t)r1 * D + kt * 64 + c1);
  };

  // Fragment addrs: lane reads row R, k-bytes [32h, 32h+32) = chunks {2h,2h+1}
  // each XOR'd with f(R) = (R>>1)&3.
  int adrA[2][2], adrB[2][2];
#pragma unroll
  for (int m = 0; m < 2; ++m) {
    int R = wm * 64 + m * 32 + l31, f = (R >> 1) & 3;
    adrA[m][0] = R * 64 + (((2 * h) ^ f) << 4);
    adrA[m][1] = R * 64 + (((2 * h + 1) ^ f) << 4);
  }
#pragma unroll
  for (int n = 0; n < 2; ++n) {
    int R = wn * 64 + n * 32 + l31, f = (R >> 1) & 3;
    adrB[n][0] = R * 64 + (((2 * h) ^ f) << 4);
    adrB[n][1] = R * 64 + (((2 * h + 1) ^ f) << 4);
  }

  f32x16 acc[2][2];
#pragma unroll
  for (int m = 0; m < 2; ++m)
#pragma unroll
    for (int n = 0; n < 2; ++n)
#pragma unroll
      for (int e = 0; e < 16; ++e) acc[m][n][e] = 0.f;

  auto compute = [&](int buf) {
    v8i a[2], bb[2];
#pragma unroll
    for (int n = 0; n < 2; ++n) {
      i32x4 x0 = *(const i32x4*)&Bs[buf][adrB[n][0]];
      i32x4 x1 = *(const i32x4*)&Bs[buf][adrB[n][1]];
      bb[n] = (v8i){x0[0], x0[1], x0[2], x0[3], x1[0], x1[1], x1[2], x1[3]};
    }
#pragma unroll
    for (int m = 0; m < 2; ++m) {
      i32x4 x0 = *(const i32x4*)&As[buf][adrA[m][0]];
      i32x4 x1 = *(const i32x4*)&As[buf][adrA[m][1]];
      a[m] = (v8i){x0[0], x0[1], x0[2], x0[3], x1[0], x1[1], x1[2], x1[3]};
    }
    __builtin_amdgcn_s_setprio(1);
#pragma unroll
    for (int m = 0; m < 2; ++m)
#pragma unroll
      for (int n = 0; n < 2; ++n)
        acc[m][n] = __builtin_amdgcn_mfma_scale_f32_32x32x64_f8f6f4(
            a[m], bb[n], acc[m][n], 0, 0, 0, 127, 0, 127);
    __builtin_amdgcn_s_setprio(0);
  };

  stage(0, 0);          // 3 loads/thread
  stage(1, 1);          // 6 outstanding
  if (tid < 128) lrow[tid] = 0.0f;
  if (tid < 256) lcol[tid] = 0.0f;

#pragma unroll
  for (int kt = 0; kt < 4; ++kt) {
    if (kt < 3) asm volatile("s_waitcnt vmcnt(3)" ::: "memory");
    else        asm volatile("s_waitcnt vmcnt(0)" ::: "memory");
    __builtin_amdgcn_s_barrier();        // tile-kt loads landed (all waves)
    __builtin_amdgcn_sched_barrier(0);
    compute(kt & 1);
    asm volatile("s_waitcnt lgkmcnt(0)" ::: "memory");
    __builtin_amdgcn_sched_barrier(0);
    __builtin_amdgcn_s_barrier();        // WAR: buffer fully consumed
    if (kt < 2) stage(kt & 1, kt + 2);
  }

  // Epilogue. 32x32 C frag: col = lane&31, row = (reg&3)+8*(reg>>2)+4*h.
  int bnW = 2 * p + (wn >> 1);
  bool wvalid = (bnW >= bm);
  bool isdiag = (bnW == bm);
  int rb0 = wm * 64;
  int clocal = (wn & 1) * 64;
  if (wvalid) {
    float ca[2] = {0.f, 0.f};
#pragma unroll
    for (int m = 0; m < 2; ++m) {
#pragma unroll
      for (int reg = 0; reg < 16; ++reg) {
        int rloc = rb0 + m * 32 + (reg & 3) + 8 * (reg >> 2) + 4 * h;
        float v = 0.f;
#pragma unroll
        for (int n = 0; n < 2; ++n) {
          float e = __expf(fmaf(acc[m][n][reg], 10.0f, -10.0f));
          if (isdiag && rloc == clocal + n * 32 + l31) e = 0.f;
          v += e;
          ca[n] += e;
        }
        v = rowsum32(v);  // DPP only (VALU pipe); result in lanes 31/63
        if (l31 == 31) atomicAdd(&lrow[rloc], v);
      }
    }
    if (!isdiag) {
#pragma unroll
      for (int n = 0; n < 2; ++n) {
        float c = ca[n];
        c += __shfl_xor(c, 32, 64);  // combine halves (same col, diff rows)
        if (h == 0) atomicAdd(&lcol[wn * 64 + n * 32 + l31], c);
      }
    }
    // pos harvest: sub-tile (bm, bm+32) local diagonal = sim[i, i+4096].
    if (bnW == bm + 32) {
#pragma unroll
      for (int m = 0; m < 2; ++m) {
#pragma unroll
        for (int n = 0; n < 2; ++n) {
          if (rb0 + m * 32 == clocal + n * 32) {
#pragma unroll
            for (int reg = 0; reg < 16; ++reg) {
              int crow = (reg & 3) + 8 * (reg >> 2) + 4 * h;
              if (crow == l31) {
                float pv = acc[m][n][reg] * INV_T;
                int gr = bm * 128 + rb0 + m * 32 + l31;
                pos[gr] = pv;
                pos[gr + N / 2] = pv;
              }
            }
          }
        }
      }
    }
  }
  __syncthreads();
  if (tid < 128) atomicAdd(&rowsum[bm * 128 + tid], lrow[tid]);
  if (tid < 256) {
    int bnX = 2 * p + (tid >> 7);
    if (bnX > bm) atomicAdd(&rowsum[bnX * 128 + (tid & 127)], lcol[tid]);
  }

  // Fused final: last block to finish reduces lse - pos to the scalar.
  __threadfence();
  if (tid == 0) {
    unsigned int o = atomicAdd(cnt, 1u);
    lastFlag = (o == NBLK - 1);
  }
  __syncthreads();
  if (lastFlag) {
    __threadfence();
    float s = 0.f;
#pragma unroll
    for (int i = 0; i < 16; ++i) {
      int idx = tid + i * 512;
      float rs = atomicAdd(&rowsum[idx], 0.0f);  // coherent read
      float pp = atomicAdd(&pos[idx], 0.0f);     // coherent read
      s += 10.0f + __logf(rs) - pp;
    }
#pragma unroll
    for (int off = 32; off; off >>= 1) s += __shfl_xor(s, off, 64);
    __shared__ float red[8];
    if (lane == 0) red[wave] = s;
    __syncthreads();
    if (tid == 0) {
      float tot = 0.f;
#pragma unroll
      for (int w = 0; w < 8; ++w) tot += red[w];
      out[0] = tot * (1.0f / N);
    }
  }
}

extern "C" void kernel_launch(void* const* d_in, const int* in_sizes, int n_in,
                              void* d_out, int out_size, void* d_ws, size_t ws_size,
                              hipStream_t stream) {
  const float* feats = (const float*)d_in[0];
  float* out = (float*)d_out;
  char* ws = (char*)d_ws;
  unsigned char* fn = (unsigned char*)ws;                      // 2 MB fp8 normalized feats
  float* pos = (float*)(ws + 2 * 1024 * 1024);                 // 32 KB
  float* rowsum = (float*)(ws + 2 * 1024 * 1024 + 32 * 1024);  // 32 KB
  unsigned int* cnt = (unsigned int*)(ws + 2 * 1024 * 1024 + 64 * 1024);

  normalize_k<<<N / 4, 256, 0, stream>>>(feats, fn, rowsum, cnt);
  gemm_lse<<<NBLK, 512, 0, stream>>>(fn, rowsum, pos, cnt, out);
}

// Round 14
// 154.726 us; speedup vs baseline: 2.0452x; 2.0452x over previous
//
#include <hip/hip_runtime.h>
#include <hip/hip_bf16.h>
#include <math.h>

typedef __attribute__((ext_vector_type(4))) float f32x4;

#define N 8192
#define D 256
#define INV_T 10.0f
#define EPSN 1e-8f
#define NBLK 1056

__device__ __forceinline__ void async16(void* lds, const void* g) {
  __builtin_amdgcn_global_load_lds(
      (const __attribute__((address_space(1))) void*)g,
      (__attribute__((address_space(3))) void*)lds,
      16, 0, 0);
}

// 16-lane-group sum via DPP row_shr (VALU pipe). Result in lane 15 of group.
__device__ __forceinline__ float rowsum16(float v) {
  v += __uint_as_float(__builtin_amdgcn_update_dpp(
      0u, __float_as_uint(v), 0x118, 0xf, 0xf, true));
  v += __uint_as_float(__builtin_amdgcn_update_dpp(
      0u, __float_as_uint(v), 0x114, 0xf, 0xf, true));
  v += __uint_as_float(__builtin_amdgcn_update_dpp(
      0u, __float_as_uint(v), 0x112, 0xf, 0xf, true));
  v += __uint_as_float(__builtin_amdgcn_update_dpp(
      0u, __float_as_uint(v), 0x111, 0xf, 0xf, true));
  return v;
}

// One wave per row: fp32 norm, fp8-e4m3 normalized row. Zeroes rowsum + cnt.
__global__ __launch_bounds__(256) void normalize_k(const float* __restrict__ feats,
                                                   unsigned char* __restrict__ fn,
                                                   float* __restrict__ rowsum,
                                                   unsigned int* __restrict__ cnt) {
  int row = blockIdx.x * 4 + (threadIdx.x >> 6);
  int lane = threadIdx.x & 63;
  if (threadIdx.x < 4) rowsum[blockIdx.x * 4 + threadIdx.x] = 0.0f;
  if (blockIdx.x == 0 && threadIdx.x == 0) *cnt = 0u;
  float4 v = ((const float4*)(feats + (size_t)row * D))[lane];
  float ss = v.x * v.x + v.y * v.y + v.z * v.z + v.w * v.w;
#pragma unroll
  for (int off = 32; off; off >>= 1) ss += __shfl_xor(ss, off, 64);
  float inv = 1.0f / fmaxf(sqrtf(ss), EPSN);
  int w = __builtin_amdgcn_cvt_pk_fp8_f32(v.x * inv, v.y * inv, 0, false);
  w = __builtin_amdgcn_cvt_pk_fp8_f32(v.z * inv, v.w * inv, w, true);
  ((int*)(fn + (size_t)row * D))[lane] = w;
}

// Fused symmetric GEMM (C = fn*fn^T/T, fp8 16x16x32) + exp(C-10) row/col sums
// + pos harvest + fused final reduction (last-block-done).
// PAIRED tiles: block = 128x256 strip (two 128^2 triangular tiles, shared A
// panel). 8 waves (2x4), each owns a 64x64 sub-output. BK=64, counted-vmcnt
// double-buffer, chunk-swizzled LDS, DPP row-reduce.
// launch_bounds (512,4): VGPR cap 128. acc(64)+operands must fit -- R11/R13
// lesson: ANY config whose accumulator+operand set exceeds the cap spills to
// scratch (100+ MB scratch traffic, 2-8x regression). fp8 16x16x32 with
// acc[4][4] f32x4 + b64 operands = ~116 VGPR: fits.
__global__ __launch_bounds__(512, 4) void gemm_lse(const unsigned char* __restrict__ fn,
                                                   float* __restrict__ rowsum,
                                                   float* __restrict__ pos,
                                                   unsigned int* __restrict__ cnt,
                                                   float* __restrict__ out) {
  __shared__ unsigned char As[2][8192];    // 128 rows x 64B
  __shared__ unsigned char Bs[2][16384];   // 256 rows x 64B
  __shared__ float lrow[128];
  __shared__ float lcol[256];              // [subtile*128 + col]
  __shared__ int lastFlag;
  __shared__ float red[8];
  int tid = threadIdx.x;
  int wave = tid >> 6, lane = tid & 63;
  int wm = wave >> 2, wn = wave & 3;
  int hi = lane >> 4, lo = lane & 15;

  // XCD-chunked order over 1056 = 8*132 blocks (bijective).
  int b = blockIdx.x;
  int t = (b & 7) * 132 + (b >> 3);
  // Pair-row mapping: rows h=0..31, each with 2*(32-h) blocks.
  int h = (int)((65.0f - sqrtf((float)(4225 - 4 * t))) * 0.5f);
  h = h < 0 ? 0 : (h > 31 ? 31 : h);
  while (t < h * (65 - h)) --h;
  while (t >= (h + 1) * (64 - h)) ++h;
  int r = t - h * (65 - h);
  int bm = 2 * h + (r & 1);   // A-panel (row) tile, 0..63
  int p = h + (r >> 1);       // B pair index: bn in {2p, 2p+1}

  const unsigned char* ga = fn + (size_t)(bm * 128) * D;
  const unsigned char* gb = fn + (size_t)(p * 256) * D;

  // Staging: chunk swizzle c' = c ^ ((r>>1)&3) within 4-chunk (64B) rows.
  int da = tid, ra = da >> 2, caa = ((da & 3) ^ ((ra >> 1) & 3)) * 16;
  int d0 = tid, r0 = d0 >> 2, c0 = ((d0 & 3) ^ ((r0 >> 1) & 3)) * 16;
  int d1 = tid + 512, r1 = d1 >> 2, c1 = ((d1 & 3) ^ ((r1 >> 1) & 3)) * 16;
  auto stage = [&](int buf, int kt) {
    async16(&As[buf][da * 16], ga + (size_t)ra * D + kt * 64 + caa);
    async16(&Bs[buf][d0 * 16], gb + (size_t)r0 * D + kt * 64 + c0);
    async16(&Bs[buf][d1 * 16], gb + (size_t)r1 * D + kt * 64 + c1);
  };

  // Fragment-read offsets: element (R,k): chunk k>>4 stored at ^((R>>1)&3).
  int offA[4][2], offB[4][2];
#pragma unroll
  for (int m = 0; m < 4; ++m) {
    int R = wm * 64 + m * 16 + lo;
#pragma unroll
    for (int ks = 0; ks < 2; ++ks)
      offA[m][ks] = R * 64 + ((((ks << 1) | (hi >> 1)) ^ ((R >> 1) & 3)) << 4) +
                    ((hi & 1) << 3);
  }
#pragma unroll
  for (int n = 0; n < 4; ++n) {
    int R = wn * 64 + n * 16 + lo;  // B row within 256-row pair panel
#pragma unroll
    for (int ks = 0; ks < 2; ++ks)
      offB[n][ks] = R * 64 + ((((ks << 1) | (hi >> 1)) ^ ((R >> 1) & 3)) << 4) +
                    ((hi & 1) << 3);
  }

  f32x4 acc[4][4];
#pragma unroll
  for (int m = 0; m < 4; ++m)
#pragma unroll
    for (int n = 0; n < 4; ++n) acc[m][n] = (f32x4){0.f, 0.f, 0.f, 0.f};

  auto compute = [&](int buf) {
#pragma unroll
    for (int ks = 0; ks < 2; ++ks) {
      long long a[4], bb[4];
#pragma unroll
      for (int m = 0; m < 4; ++m)
        a[m] = *(const long long*)&As[buf][offA[m][ks]];
#pragma unroll
      for (int n = 0; n < 4; ++n)
        bb[n] = *(const long long*)&Bs[buf][offB[n][ks]];
      __builtin_amdgcn_s_setprio(1);
#pragma unroll
      for (int m = 0; m < 4; ++m)
#pragma unroll
        for (int n = 0; n < 4; ++n)
          acc[m][n] = __builtin_amdgcn_mfma_f32_16x16x32_fp8_fp8(
              a[m], bb[n], acc[m][n], 0, 0, 0);
      __builtin_amdgcn_s_setprio(0);
    }
  };

  stage(0, 0);          // 3 loads/thread
  stage(1, 1);          // 6 outstanding
  if (tid < 128) lrow[tid] = 0.0f;
  if (tid < 256) lcol[tid] = 0.0f;

#pragma unroll
  for (int kt = 0; kt < 4; ++kt) {
    if (kt < 3) asm volatile("s_waitcnt vmcnt(3)" ::: "memory");
    else        asm volatile("s_waitcnt vmcnt(0)" ::: "memory");
    __builtin_amdgcn_s_barrier();        // tile-kt loads landed (all waves)
    __builtin_amdgcn_sched_barrier(0);
    compute(kt & 1);
    asm volatile("s_waitcnt lgkmcnt(0)" ::: "memory");
    __builtin_amdgcn_sched_barrier(0);
    __builtin_amdgcn_s_barrier();        // WAR: buffer fully consumed
    if (kt < 2) stage(kt & 1, kt + 2);
  }

  // Epilogue: wave owns 64x64 of sub-tile bnW. C frag: col=lo, row=hi*4+j.
  int bnW = 2 * p + (wn >> 1);
  bool wvalid = (bnW >= bm);
  bool isdiag = (bnW == bm);
  int rbase = wm * 64;
  int clocal = (wn & 1) * 64;  // col base within the 128-col sub-tile
  if (wvalid) {
    float ca[4] = {0.f, 0.f, 0.f, 0.f};
#pragma unroll
    for (int m = 0; m < 4; ++m) {
#pragma unroll
      for (int j = 0; j < 4; ++j) {
        int rloc = rbase + m * 16 + hi * 4 + j;
        float v = 0.f;
#pragma unroll
        for (int n = 0; n < 4; ++n) {
          float e = __expf(fmaf(acc[m][n][j], 10.0f, -10.0f));
          if (isdiag && rloc == clocal + n * 16 + lo) e = 0.f;
          v += e;
          ca[n] += e;
        }
        v = rowsum16(v);
        if (lo == 15) atomicAdd(&lrow[rloc], v);
      }
    }
    if (!isdiag) {
#pragma unroll
      for (int n = 0; n < 4; ++n) {
        float c = ca[n];
        c += __shfl_xor(c, 16, 64);
        c += __shfl_xor(c, 32, 64);
        if (hi == 0) atomicAdd(&lcol[wn * 64 + n * 16 + lo], c);
      }
    }
    // pos harvest: sub-tile (bm, bm+32): local diagonal = sim[i, i+4096].
    if (bnW == bm + 32) {
#pragma unroll
      for (int m = 0; m < 4; ++m) {
#pragma unroll
        for (int n = 0; n < 4; ++n) {
          if (wm * 64 + m * 16 == clocal + n * 16 && (lo >> 2) == hi) {
            int j = lo & 3;
            f32x4 a = acc[m][n];
            float pv = (j == 0) ? a[0] : (j == 1) ? a[1] : (j == 2) ? a[2] : a[3];
            pv *= INV_T;
            int gr = bm * 128 + wm * 64 + m * 16 + lo;
            pos[gr] = pv;
            pos[gr + N / 2] = pv;
          }
        }
      }
    }
  }
  __syncthreads();
  if (tid < 128) atomicAdd(&rowsum[bm * 128 + tid], lrow[tid]);
  if (tid < 256) {
    int bnX = 2 * p + (tid >> 7);
    if (bnX > bm) atomicAdd(&rowsum[bnX * 128 + (tid & 127)], lcol[tid]);
  }

  // Fused final: last block to finish reduces lse - pos to the scalar.
  __threadfence();
  if (tid == 0) {
    unsigned int o = atomicAdd(cnt, 1u);
    lastFlag = (o == NBLK - 1);
  }
  __syncthreads();
  if (lastFlag) {
    __threadfence();
    float s = 0.f;
#pragma unroll
    for (int i = 0; i < 16; ++i) {
      int idx = tid + i * 512;
      float rs = atomicAdd(&rowsum[idx], 0.0f);  // coherent (device-scope) read
      float pp = atomicAdd(&pos[idx], 0.0f);     // coherent (device-scope) read
      s += 10.0f + __logf(rs) - pp;
    }
#pragma unroll
    for (int off = 32; off; off >>= 1) s += __shfl_xor(s, off, 64);
    if (lane == 0) red[wave] = s;
    __syncthreads();
    if (tid == 0) {
      float tot = 0.f;
#pragma unroll
      for (int w = 0; w < 8; ++w) tot += red[w];
      out[0] = tot * (1.0f / N);
    }
  }
}

extern "C" void kernel_launch(void* const* d_in, const int* in_sizes, int n_in,
                              void* d_out, int out_size, void* d_ws, size_t ws_size,
                              hipStream_t stream) {
  const float* feats = (const float*)d_in[0];
  float* out = (float*)d_out;
  char* ws = (char*)d_ws;
  unsigned char* fn = (unsigned char*)ws;                      // 2 MB fp8 normalized feats
  float* pos = (float*)(ws + 2 * 1024 * 1024);                 // 32 KB
  float* rowsum = (float*)(ws + 2 * 1024 * 1024 + 32 * 1024);  // 32 KB
  unsigned int* cnt = (unsigned int*)(ws + 2 * 1024 * 1024 + 64 * 1024);

  normalize_k<<<N / 4, 256, 0, stream>>>(feats, fn, rowsum, cnt);
  gemm_lse<<<NBLK, 512, 0, stream>>>(fn, rowsum, pos, cnt, out);
}